// Round 4
// baseline (105.762 us; speedup 1.0000x reference)
//
#include <hip/hip_runtime.h>
#include <math.h>

#define NBOX 4096
#define TILE 32
#define NT (NBOX / TILE)               // 128
#define NTRI (NT * (NT + 1) / 2)       // 8256 upper-triangle tiles
#define NBLK (NTRI / 4)                // 2064 WGs, 4 tiles per 512-thread WG
#define SS 12                          // struct stride in floats (48 B)
#define JB 400                         // J region base within a slice
#define SLICE 800                      // floats per tile slice (I@0, J@JB)

typedef float v2f __attribute__((ext_vector_type(2)));
typedef float vf4 __attribute__((ext_vector_type(4)));

// LDS per-box layout (10 used floats, stride 12), packed for v_pk_fma_f32:
// [0]a0x [1]a1x [2]a0y [3]a1y | [4]sc0 [5]sc1 [6]l0 [7]l1 | [8]cx [9]cy

struct Box {
    v2f A0, A1, SC, LL;
    float cx, cy;
};

__device__ __forceinline__ float rcp_fast(float x) { return __builtin_amdgcn_rcpf(x); }
__device__ __forceinline__ v2f splat(float s) { return (v2f){s, s}; }
__device__ __forceinline__ v2f fma2(v2f a, v2f b, v2f c) { return __builtin_elementwise_fma(a, b, c); }
__device__ __forceinline__ v2f abs2(v2f a) { return __builtin_elementwise_abs(a); }
__device__ __forceinline__ v2f min2(v2f a, v2f b) { return __builtin_elementwise_min(a, b); }

// Exact identities: overlap r = min(H1, H2, (H1+H2)/2 - |D|)  (signed)
//                   giou1d  g = r / (S - r),  S = H1 + H2 > 0,  r <= S/2
// Single-division tail: m_i = r_i * P / S_i with P = S0*S1*S2*S3.
// x/(P-x) is increasing, so min_i g_i = m*/(P - m*) with m* = min_i m_i.
// r <= S/2 => P - m* >= P/2 (no cancellation); P <= ~243^4 = 3.5e9 (f32 ok).
__device__ __forceinline__ float mgiou_pair(const Box& I, const Box& J) {
    v2f dA = fma2(I.A0, splat(J.A0.x), I.A1 * J.A1.x);   // (u0.v0, u1.v0)
    v2f dB = fma2(I.A0, splat(J.A0.y), I.A1 * J.A1.y);   // (u0.v1, u1.v1)
    v2f DI = fma2(I.A0, splat(J.cx), fma2(I.A1, splat(J.cy), -I.SC));
    v2f DJ = fma2(J.A0, splat(I.cx), fma2(J.A1, splat(I.cy), -J.SC));
    v2f aA = abs2(dA), aB = abs2(dB);
    v2f HI = aA + aB;                                   // J extents on I axes
    v2f HJ = (v2f){aA.x, aB.x} + (v2f){aA.y, aB.y};     // I extents on J axes
    v2f SI = I.LL + HI;
    v2f SJ = J.LL + HJ;
    v2f uI = fma2(splat(0.5f), SI, -abs2(DI));
    v2f uJ = fma2(splat(0.5f), SJ, -abs2(DJ));
    v2f rI = min2(min2(I.LL, HI), uI);
    v2f rJ = min2(min2(J.LL, HJ), uJ);
    float S01 = SI.x * SI.y, S23 = SJ.x * SJ.y;
    float P = S01 * S23;
    v2f mI = rI * (v2f){SI.y, SI.x} * splat(S23);
    v2f mJ = rJ * (v2f){SJ.y, SJ.x} * splat(S01);
    float mm = fminf(fminf(mI.x, mI.y), fminf(mJ.x, mJ.y));
    return fmaxf(mm, 0.0f) * rcp_fast(P - mm);
}

// Cumulative swizzle (+4 floats per 8-struct octet, monotone, no overlap).
// Even-struct b128 reads across 16 lanes: offsets mod 32 land exactly 2-way
// per bank-group (wave64 floor, free); odd-struct reads likewise.
__device__ __forceinline__ int sw_offset(int i) { return i * SS + (i >> 3) * 4; }

__device__ __forceinline__ Box load_box(const float* p) {
    Box b;
    float4 x = *(const float4*)(p);
    float4 y = *(const float4*)(p + 4);
    float2 z = *(const float2*)(p + 8);
    b.A0 = (v2f){x.x, x.y}; b.A1 = (v2f){x.z, x.w};
    b.SC = (v2f){y.x, y.y}; b.LL = (v2f){y.z, y.w};
    b.cx = z.x; b.cy = z.y;
    return b;
}

__device__ __forceinline__ void decode_tri(int k, int& bi, int& bj) {
    bi = (int)((float)(2 * NT + 1 - sqrtf((float)((2 * NT + 1) * (2 * NT + 1) - 8 * k))) * 0.5f);
    if (bi > 0 && k < bi * NT - bi * (bi - 1) / 2) bi--;
    if (k >= (bi + 1) * NT - (bi + 1) * bi / 2) bi++;
    bj = bi + (k - (bi * NT - bi * (bi - 1) / 2));
}

// R16->R17: all write-side theories falsified (chunk size R15, streams R15,
// nt/L2 R16 — all neutral). Kernel is compute-side bound at ~2.7x the issue
// model => latency/occupancy stalls suspected. This round: (1) 8-wave WGs
// (4 tiles, 2 waves/tile) kill the 16-WG/CU slot cap; (2) VGPR<=64 forced
// via __launch_bounds__(512,8) (J[2]+vT[2][4] per lane, ~50 live) => 8
// waves/SIMD, 2x occupancy; (3) single-rcp product tail (~-15% per-pair).
// Predict: latency-bound -> 74-77; issue-bound -> 78-79; else neutral 81.
__global__ __launch_bounds__(512, 8)
void pairwise_kernel(const float* __restrict__ boxes, float* __restrict__ out) {
    __shared__ float sm[4 * SLICE];     // 4 tile slices x (32 I + 32 J structs)

    int tid = threadIdx.x;
    if (tid < 256) {   // stage: thread group (tid>>6) builds slice's 64 structs? no:
        // 256 threads = 4 groups of 64; group sid stages slice sid (64 box structs)
        int sid = tid >> 6, loc = tid & 63;
        int kP = 4 * blockIdx.x + sid;
        int biP, bjP; decode_tri(kP, biP, bjP);
        int box = ((loc < TILE) ? biP : bjP) * TILE + (loc & (TILE - 1));
        float cx = boxes[box * 5 + 0];
        float cy = boxes[box * 5 + 1];
        float w  = boxes[box * 5 + 2];
        float h  = boxes[box * 5 + 3];
        float ang = boxes[box * 5 + 4];
        float s, c;
        __sincosf(ang, &s, &c);
        float a0x = w * c, a0y = -w * s;    // full edge vectors (match ref rot)
        float a1x = h * s, a1y =  h * c;
        float sc0 = fmaf(a0x, cx, a0y * cy);
        float sc1 = fmaf(a1x, cx, a1y * cy);
        float* d = &sm[sid * SLICE + ((loc < TILE) ? 0 : JB) + sw_offset(loc & (TILE - 1))];
        ((float4*)d)[0] = make_float4(a0x, a1x, a0y, a1y);
        ((float4*)d)[1] = make_float4(sc0, sc1, w * w, h * h);
        ((float2*)d)[4] = make_float2(cx, cy);
    }
    __syncthreads();

    int w8 = tid >> 6;          // wave 0..7
    int s = w8 >> 1;            // tile slice 0..3
    int hf = w8 & 1;            // row half: rows 16*hf .. 16*hf+15
    int lane = tid & 63;
    int jq = lane & 15;         // col pair: cols 2jq, 2jq+1 (32 cols)
    int tg = lane >> 4;         // row quad within the half (0..3)
    int rbase = 16 * hf + 4 * tg;   // lane's 4 rows: rbase .. rbase+3

    int k = 4 * blockIdx.x + s;
    int bi, bj; decode_tri(k, bi, bj);

    const float* base = &sm[s * SLICE];
    Box J0 = load_box(base + JB + sw_offset(2 * jq));
    Box J1 = load_box(base + JB + sw_offset(2 * jq + 1));

    int ibase = bi * TILE, jbase = bj * TILE;
    const float* ip = base + sw_offset(rbase);   // rbase..rbase+3 share an octet
    float vT[2][4];

    #pragma unroll
    for (int kk = 0; kk < 4; ++kk) {
        Box I = load_box(ip + kk * SS);
        int ig = ibase + rbase + kk;
        int jg0 = jbase + 2 * jq;
        float v0 = (ig == jg0)     ? 0.0f : mgiou_pair(I, J0);
        float v1 = (ig == jg0 + 1) ? 0.0f : mgiou_pair(I, J1);
        vT[0][kk] = v0; vT[1][kk] = v1;
        // upper: per instr, 4 i-rows x (16 lanes x 8 B = 128 B contiguous)
        v2f o = {v0, v1};
        *(v2f*)&out[(size_t)ig * NBOX + jg0] = o;
    }

    if (bi != bj) {
        // mirror: lane-local 16 B along i; values already register-resident
        #pragma unroll
        for (int m = 0; m < 2; ++m) {
            int jg = jbase + 2 * jq + m;
            vf4 o = {vT[m][0], vT[m][1], vT[m][2], vT[m][3]};
            *(vf4*)&out[(size_t)jg * NBOX + ibase + rbase] = o;
        }
    }
}

extern "C" void kernel_launch(void* const* d_in, const int* in_sizes, int n_in,
                              void* d_out, int out_size, void* d_ws, size_t ws_size,
                              hipStream_t stream) {
    const float* boxes = (const float*)d_in[0];
    float* out = (float*)d_out;
    pairwise_kernel<<<dim3(NBLK), dim3(512), 0, stream>>>(boxes, out);
}